// Round 1
// baseline (99.882 us; speedup 1.0000x reference)
//
#include <hip/hip_runtime.h>
#include <stdint.h>

// SHA-256 round constants (compile-time; folds to literals under full unroll)
constexpr uint32_t Kc[64] = {
    1116352408u, 1899447441u, 3049323471u, 3921009573u,  961987163u, 1508970993u,
    2453635748u, 2870763221u, 3624381080u,  310598401u,  607225278u, 1426881987u,
    1925078388u, 2162078206u, 2614888103u, 3248222580u, 3835390401u, 4022224774u,
     264347078u,  604807628u,  770255983u, 1249150122u, 1555081692u, 1996064986u,
    2554220882u, 2821834349u, 2952996808u, 3210313671u, 3336571891u, 3584528711u,
     113926993u,  338241895u,  666307205u,  773529912u, 1294757372u, 1396182291u,
    1695183700u, 1986661051u, 2177026350u, 2456956037u, 2730485921u, 2820302411u,
    3259730800u, 3345764771u, 3516065817u, 3600352804u, 4094571909u,  275423344u,
     430227734u,  506948616u,  659060556u,  883997877u,  958139571u, 1322822218u,
    1537002063u, 1747873779u, 1955562222u, 2024104815u, 2227730452u, 2361852424u,
    2428436474u, 2756734187u, 3204031479u, 3329325298u
};

constexpr uint32_t H0c[8] = {
    1779033703u, 3144134277u, 1013904242u, 2773480762u,
    1359893119u, 2600822924u,  528734635u, 1541459225u
};

__device__ __forceinline__ uint32_t rotr32(uint32_t x, int n) {
    // compiler emits v_alignbit_b32 (single instruction)
    return (x >> n) | (x << (32 - n));
}

__global__ __launch_bounds__(256) void sha256_kernel(
        const int* __restrict__ msg, uint32_t* __restrict__ out, int n) {
    const uint32_t tid = blockIdx.x * blockDim.x + threadIdx.x;
    if (tid >= (uint32_t)n) return;

    // Each message: 64 bytes, stored one byte per int32. 64 int32 = 256 B,
    // int4-aligned at tid*256. Pack 4 byte-ints -> one big-endian 32-bit word.
    const int4* m4 = reinterpret_cast<const int4*>(msg) + (size_t)tid * 16;

    uint32_t W[16];
#pragma unroll
    for (int i = 0; i < 16; ++i) {
        int4 v = m4[i];
        W[i] = ((uint32_t)v.x << 24) | ((uint32_t)v.y << 16) |
               ((uint32_t)v.z << 8)  |  (uint32_t)v.w;
    }

    uint32_t a = H0c[0], b = H0c[1], c = H0c[2], d = H0c[3];
    uint32_t e = H0c[4], f = H0c[5], g = H0c[6], h = H0c[7];

#pragma unroll
    for (int i = 0; i < 64; ++i) {
        uint32_t wi;
        if (i < 16) {
            wi = W[i];
        } else {
            // rolling 16-word schedule window (all indices constant after unroll)
            uint32_t x15 = W[(i - 15) & 15];
            uint32_t x2  = W[(i - 2) & 15];
            uint32_t s0 = rotr32(x15, 7) ^ rotr32(x15, 18) ^ (x15 >> 3);
            uint32_t s1 = rotr32(x2, 17) ^ rotr32(x2, 19) ^ (x2 >> 10);
            wi = W[i & 15] + s0 + W[(i - 7) & 15] + s1;
            W[i & 15] = wi;
        }
        uint32_t S1  = rotr32(e, 6) ^ rotr32(e, 11) ^ rotr32(e, 25);
        uint32_t ch  = (e & f) ^ (~e & g);            // -> v_bfi_b32
        uint32_t t1  = h + S1 + ch + Kc[i] + wi;      // -> v_add3_u32 chains
        uint32_t S0  = rotr32(a, 2) ^ rotr32(a, 13) ^ rotr32(a, 22);
        uint32_t maj = (a & b) ^ (a & c) ^ (b & c);
        uint32_t t2  = S0 + maj;
        h = g; g = f; f = e;
        e = d + t1;
        d = c; c = b; b = a;
        a = t1 + t2;
    }

    // Output: (B, 8) uint32 words, row-major -> 32 contiguous bytes/thread.
    // Harness reads d_out as int32; write raw 32-bit words.
    uint4* o = reinterpret_cast<uint4*>(out) + (size_t)tid * 2;
    o[0] = make_uint4(H0c[0] + a, H0c[1] + b, H0c[2] + c, H0c[3] + d);
    o[1] = make_uint4(H0c[4] + e, H0c[5] + f, H0c[6] + g, H0c[7] + h);
}

extern "C" void kernel_launch(void* const* d_in, const int* in_sizes, int n_in,
                              void* d_out, int out_size, void* d_ws, size_t ws_size,
                              hipStream_t stream) {
    const int* msg = (const int*)d_in[0];
    uint32_t* out = (uint32_t*)d_out;
    const int n = in_sizes[0] / 64;   // messages (B)
    const int block = 256;
    const int grid = (n + block - 1) / block;
    sha256_kernel<<<grid, block, 0, stream>>>(msg, out, n);
}

// Round 2
// 99.384 us; speedup vs baseline: 1.0050x; 1.0050x over previous
//
#include <hip/hip_runtime.h>
#include <stdint.h>

// SHA-256 round constants — used as compile-time literals via Kc[<const>]
constexpr uint32_t Kc[64] = {
    1116352408u, 1899447441u, 3049323471u, 3921009573u,  961987163u, 1508970993u,
    2453635748u, 2870763221u, 3624381080u,  310598401u,  607225278u, 1426881987u,
    1925078388u, 2162078206u, 2614888103u, 3248222580u, 3835390401u, 4022224774u,
     264347078u,  604807628u,  770255983u, 1249150122u, 1555081692u, 1996064986u,
    2554220882u, 2821834349u, 2952996808u, 3210313671u, 3336571891u, 3584528711u,
     113926993u,  338241895u,  666307205u,  773529912u, 1294757372u, 1396182291u,
    1695183700u, 1986661051u, 2177026350u, 2456956037u, 2730485921u, 2820302411u,
    3259730800u, 3345764771u, 3516065817u, 3600352804u, 4094571909u,  275423344u,
     430227734u,  506948616u,  659060556u,  883997877u,  958139571u, 1322822218u,
    1537002063u, 1747873779u, 1955562222u, 2024104815u, 2227730452u, 2361852424u,
    2428436474u, 2756734187u, 3204031479u, 3329325298u
};

#define ROTR(x,n) (((x) >> (n)) | ((x) << (32 - (n))))

// One round. Register names rotate by the caller, so no shift-moves needed.
// maj trick: maj(a,b,c) = b ^ ((a^b) & (b^c)); (b^c) this round == (a^b) of
// the previous round, carried in `xab` (1 xor + 1 and + 1 xor vs 5 ops).
// ch = (e&f)^(~e&g) pattern-matches v_bfi_b32.
#define RND(a,b,c,d,e,f,g,h,K,w) {                                        \
    uint32_t t1 = h + (ROTR(e,6) ^ ROTR(e,11) ^ ROTR(e,25))               \
                    + ((e & f) ^ (~e & g)) + (K) + (w);                   \
    uint32_t nx = a ^ b;                                                  \
    uint32_t t2 = (ROTR(a,2) ^ ROTR(a,13) ^ ROTR(a,22)) + (b ^ (nx & xab)); \
    xab = nx;                                                             \
    d += t1; h = t1 + t2; }

#define R0(K,w) RND(a,b,c,d,e,f,g,h,K,w)
#define R1(K,w) RND(h,a,b,c,d,e,f,g,K,w)
#define R2(K,w) RND(g,h,a,b,c,d,e,f,K,w)
#define R3(K,w) RND(f,g,h,a,b,c,d,e,K,w)
#define R4(K,w) RND(e,f,g,h,a,b,c,d,K,w)
#define R5(K,w) RND(d,e,f,g,h,a,b,c,K,w)
#define R6(K,w) RND(c,d,e,f,g,h,a,b,K,w)
#define R7(K,w) RND(b,c,d,e,f,g,h,a,K,w)

// Schedule expansion: wA += s0(wB) + wC + s1(wD)
#define WEXP(wA,wB,wC,wD)                                                 \
    wA += (ROTR(wB,7) ^ ROTR(wB,18) ^ ((wB) >> 3)) + (wC)                 \
        + (ROTR(wD,17) ^ ROTR(wD,19) ^ ((wD) >> 10));

__device__ __forceinline__ uint32_t pack_be(int4 v) {
    return ((uint32_t)v.x << 24) | ((uint32_t)v.y << 16) |
           ((uint32_t)v.z << 8)  |  (uint32_t)v.w;
}

__global__ __launch_bounds__(256) void sha256_kernel(
        const int* __restrict__ msg, uint32_t* __restrict__ out, int n) {
    const uint32_t tid = blockIdx.x * blockDim.x + threadIdx.x;
    if (tid >= (uint32_t)n) return;

    // 64 bytes/message, one byte per int32 -> 16 int4 loads, pack big-endian.
    const int4* m4 = reinterpret_cast<const int4*>(msg) + (size_t)tid * 16;

    uint32_t w0  = pack_be(m4[0]),  w1  = pack_be(m4[1]);
    uint32_t w2  = pack_be(m4[2]),  w3  = pack_be(m4[3]);
    uint32_t w4  = pack_be(m4[4]),  w5  = pack_be(m4[5]);
    uint32_t w6  = pack_be(m4[6]),  w7  = pack_be(m4[7]);
    uint32_t w8  = pack_be(m4[8]),  w9  = pack_be(m4[9]);
    uint32_t w10 = pack_be(m4[10]), w11 = pack_be(m4[11]);
    uint32_t w12 = pack_be(m4[12]), w13 = pack_be(m4[13]);
    uint32_t w14 = pack_be(m4[14]), w15 = pack_be(m4[15]);

    uint32_t a = 1779033703u, b = 3144134277u, c = 1013904242u, d = 2773480762u;
    uint32_t e = 1359893119u, f = 2600822924u, g =  528734635u, h = 1541459225u;
    uint32_t xab = b ^ c;   // (b^c) entering round 0

    // Rounds 0..15
    R0(Kc[0],w0)  R1(Kc[1],w1)  R2(Kc[2],w2)  R3(Kc[3],w3)
    R4(Kc[4],w4)  R5(Kc[5],w5)  R6(Kc[6],w6)  R7(Kc[7],w7)
    R0(Kc[8],w8)  R1(Kc[9],w9)  R2(Kc[10],w10) R3(Kc[11],w11)
    R4(Kc[12],w12) R5(Kc[13],w13) R6(Kc[14],w14) R7(Kc[15],w15)

    // Rounds 16..63: expand-then-round, rolling 16-word window
    WEXP(w0,w1,w9,w14)    R0(Kc[16],w0)
    WEXP(w1,w2,w10,w15)   R1(Kc[17],w1)
    WEXP(w2,w3,w11,w0)    R2(Kc[18],w2)
    WEXP(w3,w4,w12,w1)    R3(Kc[19],w3)
    WEXP(w4,w5,w13,w2)    R4(Kc[20],w4)
    WEXP(w5,w6,w14,w3)    R5(Kc[21],w5)
    WEXP(w6,w7,w15,w4)    R6(Kc[22],w6)
    WEXP(w7,w8,w0,w5)     R7(Kc[23],w7)
    WEXP(w8,w9,w1,w6)     R0(Kc[24],w8)
    WEXP(w9,w10,w2,w7)    R1(Kc[25],w9)
    WEXP(w10,w11,w3,w8)   R2(Kc[26],w10)
    WEXP(w11,w12,w4,w9)   R3(Kc[27],w11)
    WEXP(w12,w13,w5,w10)  R4(Kc[28],w12)
    WEXP(w13,w14,w6,w11)  R5(Kc[29],w13)
    WEXP(w14,w15,w7,w12)  R6(Kc[30],w14)
    WEXP(w15,w0,w8,w13)   R7(Kc[31],w15)

    WEXP(w0,w1,w9,w14)    R0(Kc[32],w0)
    WEXP(w1,w2,w10,w15)   R1(Kc[33],w1)
    WEXP(w2,w3,w11,w0)    R2(Kc[34],w2)
    WEXP(w3,w4,w12,w1)    R3(Kc[35],w3)
    WEXP(w4,w5,w13,w2)    R4(Kc[36],w4)
    WEXP(w5,w6,w14,w3)    R5(Kc[37],w5)
    WEXP(w6,w7,w15,w4)    R6(Kc[38],w6)
    WEXP(w7,w8,w0,w5)     R7(Kc[39],w7)
    WEXP(w8,w9,w1,w6)     R0(Kc[40],w8)
    WEXP(w9,w10,w2,w7)    R1(Kc[41],w9)
    WEXP(w10,w11,w3,w8)   R2(Kc[42],w10)
    WEXP(w11,w12,w4,w9)   R3(Kc[43],w11)
    WEXP(w12,w13,w5,w10)  R4(Kc[44],w12)
    WEXP(w13,w14,w6,w11)  R5(Kc[45],w13)
    WEXP(w14,w15,w7,w12)  R6(Kc[46],w14)
    WEXP(w15,w0,w8,w13)   R7(Kc[47],w15)

    WEXP(w0,w1,w9,w14)    R0(Kc[48],w0)
    WEXP(w1,w2,w10,w15)   R1(Kc[49],w1)
    WEXP(w2,w3,w11,w0)    R2(Kc[50],w2)
    WEXP(w3,w4,w12,w1)    R3(Kc[51],w3)
    WEXP(w4,w5,w13,w2)    R4(Kc[52],w4)
    WEXP(w5,w6,w14,w3)    R5(Kc[53],w5)
    WEXP(w6,w7,w15,w4)    R6(Kc[54],w6)
    WEXP(w7,w8,w0,w5)     R7(Kc[55],w7)
    WEXP(w8,w9,w1,w6)     R0(Kc[56],w8)
    WEXP(w9,w10,w2,w7)    R1(Kc[57],w9)
    WEXP(w10,w11,w3,w8)   R2(Kc[58],w10)
    WEXP(w11,w12,w4,w9)   R3(Kc[59],w11)
    WEXP(w12,w13,w5,w10)  R4(Kc[60],w12)
    WEXP(w13,w14,w6,w11)  R5(Kc[61],w13)
    WEXP(w14,w15,w7,w12)  R6(Kc[62],w14)
    WEXP(w15,w0,w8,w13)   R7(Kc[63],w15)

    // Output: (B, 8) raw uint32 words, 32 contiguous bytes per thread.
    uint4* o = reinterpret_cast<uint4*>(out) + (size_t)tid * 2;
    o[0] = make_uint4(1779033703u + a, 3144134277u + b,
                      1013904242u + c, 2773480762u + d);
    o[1] = make_uint4(1359893119u + e, 2600822924u + f,
                       528734635u + g, 1541459225u + h);
}

extern "C" void kernel_launch(void* const* d_in, const int* in_sizes, int n_in,
                              void* d_out, int out_size, void* d_ws, size_t ws_size,
                              hipStream_t stream) {
    const int* msg = (const int*)d_in[0];
    uint32_t* out = (uint32_t*)d_out;
    const int n = in_sizes[0] / 64;   // B messages
    const int block = 256;
    const int grid = (n + block - 1) / block;
    sha256_kernel<<<grid, block, 0, stream>>>(msg, out, n);
}